// Round 8
// baseline (871.729 us; speedup 1.0000x reference)
//
#include <hip/hip_runtime.h>
#include <math.h>

// Problem constants (match reference)
#define D_IN 17
#define DH   32      // hidden dim = H*C
#define TDIM 32
#define TABK 4096    // time-encoding table resolution (nearest-neighbor)

#define NBSH 7                   // nodes per bucket = 128
#define BNODES (1 << NBSH)
#define NBKMAX 1024              // max buckets supported
#define TILE 8192                // edges per tile block (bcount / s1)
#define QSTR 33                  // LDS q stride (pad -> conflict-free b128 reads)
#define ASTR 37                  // LDS accumulator stride (32ch + 2 sums + pad)

// LDS weight pack offsets (floats) for node_prep
#define WL_OFF 0        // 32*17
#define BL_OFF 544
#define WQ_OFF 576      // 32*32
#define BQ_OFF 1600
#define WK_OFF 1632
#define BK_OFF 2656
#define WV_OFF 2688
#define BV_OFF 3712
#define WS_OFF 3744
#define BS_OFF 4768
#define WTOT   4800

__device__ __forceinline__ unsigned int f2bf(float x) {
    unsigned int u = __float_as_uint(x);
    return (u + 0x7fffu + ((u >> 16) & 1u)) >> 16;   // RTNE, no NaN expected
}
__device__ __forceinline__ float bfl(unsigned int u) { return __uint_as_float(u << 16); }
__device__ __forceinline__ float bfh(unsigned int u) { return __uint_as_float(u & 0xffff0000u); }

// ---------------------------------------------------------------------------
// Kernel 1: h1 = relu(x@Wl.T+bl); q (f32, pre-scaled by 0.25), k/v packed bf16
//           (128B/row), skip f32. block 0 also zeroes bcnt.
// ---------------------------------------------------------------------------
__global__ __launch_bounds__(256) void node_prep(
    const float* __restrict__ x,
    const float* __restrict__ Wl, const float* __restrict__ bl,
    const float* __restrict__ Wq, const float* __restrict__ bq,
    const float* __restrict__ Wk, const float* __restrict__ bk,
    const float* __restrict__ Wv, const float* __restrict__ bv,
    const float* __restrict__ Ws, const float* __restrict__ bs,
    float* __restrict__ qn, unsigned short* __restrict__ kvn,
    float* __restrict__ skv, int* __restrict__ bcnt, int N)
{
    if (blockIdx.x == 0) {
        for (int i = threadIdx.x; i < NBKMAX; i += 256) bcnt[i] = 0;
    }

    __shared__ float w[WTOT];
    {
        const float* srcs[10] = {Wl, bl, Wq, bq, Wk, bk, Wv, bv, Ws, bs};
        const int   sizes[10] = {544, 32, 1024, 32, 1024, 32, 1024, 32, 1024, 32};
        int off = 0;
        for (int seg = 0; seg < 10; ++seg) {
            const float* p = srcs[seg];
            int sz = sizes[seg];
            for (int i = threadIdx.x; i < sz; i += blockDim.x) w[off + i] = p[i];
            off += sz;
        }
    }
    __syncthreads();

    int n = blockIdx.x * blockDim.x + threadIdx.x;
    if (n >= N) return;

    float xv[D_IN];
#pragma unroll
    for (int j = 0; j < D_IN; ++j) xv[j] = x[(size_t)n * D_IN + j];

    float h1[DH];
#pragma unroll
    for (int i = 0; i < DH; ++i) {
        float acc = w[BL_OFF + i];
#pragma unroll
        for (int j = 0; j < D_IN; ++j) acc += xv[j] * w[WL_OFF + i * D_IN + j];
        h1[i] = fmaxf(acc, 0.0f);
    }

    float outr[DH];

#define MATVEC(WO, BO)                                                       \
    {                                                                        \
        _Pragma("unroll")                                                    \
        for (int i = 0; i < DH; ++i) {                                       \
            float acc = w[(BO) + i];                                         \
            _Pragma("unroll")                                                \
            for (int c = 0; c < 8; ++c) {                                    \
                float4 wv = *(const float4*)&w[(WO) + i * DH + c * 4];       \
                acc += h1[c * 4 + 0] * wv.x + h1[c * 4 + 1] * wv.y           \
                     + h1[c * 4 + 2] * wv.z + h1[c * 4 + 3] * wv.w;          \
            }                                                                \
            outr[i] = acc;                                                   \
        }                                                                    \
    }

    // q -> f32 (scaled by 1/sqrt(C)=0.25, folded here)
    MATVEC(WQ_OFF, BQ_OFF)
    {
        float4* dst4 = (float4*)(qn + (size_t)n * DH);
#pragma unroll
        for (int c = 0; c < 8; ++c) {
            float4 o; o.x = outr[c*4+0] * 0.25f; o.y = outr[c*4+1] * 0.25f;
            o.z = outr[c*4+2] * 0.25f; o.w = outr[c*4+3] * 0.25f;
            dst4[c] = o;
        }
    }

    // k -> bf16 packed words 0..15
    unsigned int kw[16], vw[16];
    MATVEC(WK_OFF, BK_OFF)
#pragma unroll
    for (int i = 0; i < 16; ++i)
        kw[i] = f2bf(outr[2*i]) | (f2bf(outr[2*i+1]) << 16);

    // v -> bf16 packed words 16..31
    MATVEC(WV_OFF, BV_OFF)
#pragma unroll
    for (int i = 0; i < 16; ++i)
        vw[i] = f2bf(outr[2*i]) | (f2bf(outr[2*i+1]) << 16);

    {
        uint4* row = (uint4*)(kvn + (size_t)n * 64);
#pragma unroll
        for (int c = 0; c < 4; ++c) {
            uint4 o; o.x = kw[c*4+0]; o.y = kw[c*4+1]; o.z = kw[c*4+2]; o.w = kw[c*4+3];
            row[c] = o;
        }
#pragma unroll
        for (int c = 0; c < 4; ++c) {
            uint4 o; o.x = vw[c*4+0]; o.y = vw[c*4+1]; o.z = vw[c*4+2]; o.w = vw[c*4+3];
            row[4 + c] = o;
        }
    }

    // skip -> f32
    MATVEC(WS_OFF, BS_OFF)
    {
        float4* dst4 = (float4*)(skv + (size_t)n * DH);
#pragma unroll
        for (int c = 0; c < 8; ++c) {
            float4 o; o.x = outr[c*4+0]; o.y = outr[c*4+1];
            o.z = outr[c*4+2]; o.w = outr[c*4+3];
            dst4[c] = o;
        }
    }
#undef MATVEC
}

// ---------------------------------------------------------------------------
// Kernel 2: time-encoding lookup table (TABK+1 rows, nearest-neighbor use)
// ---------------------------------------------------------------------------
__global__ __launch_bounds__(64) void build_table(
    const float* __restrict__ We, const float* __restrict__ be,
    const float* __restrict__ freq, const float* __restrict__ phase,
    float* __restrict__ table)
{
    int k = blockIdx.x * blockDim.x + threadIdx.x;
    if (k > TABK) return;
    float r = -1.0f + 2.0f * (float)k / (float)TABK;
    float cj[TDIM];
#pragma unroll
    for (int j = 0; j < TDIM; ++j) cj[j] = cosf(r * freq[j] + phase[j]);
#pragma unroll 4
    for (int o = 0; o < DH; ++o) {
        float acc = be[o];
#pragma unroll
        for (int j = 0; j < TDIM; ++j) acc += cj[j] * We[o * TDIM + j];
        table[(size_t)k * DH + o] = acc;
    }
}

// ---------------------------------------------------------------------------
// bcount: coarse-bucket histogram (LDS-aggregated)
// ---------------------------------------------------------------------------
__global__ __launch_bounds__(256) void bcount_k(
    const int* __restrict__ ei, int* __restrict__ bcnt, int E, int NBK)
{
    __shared__ int lc[NBKMAX];
    for (int i = threadIdx.x; i < NBKMAX; i += 256) lc[i] = 0;
    __syncthreads();
    int base = blockIdx.x * TILE;
#pragma unroll 4
    for (int i = 0; i < TILE / 256; ++i) {
        int e = base + i * 256 + threadIdx.x;
        if (e < E) atomicAdd(&lc[((unsigned int)ei[E + e]) >> NBSH], 1);
    }
    __syncthreads();
    for (int b = threadIdx.x; b < NBK; b += 256) {
        int c = lc[b];
        if (c) atomicAdd(&bcnt[b], c);
    }
}

// ---------------------------------------------------------------------------
// bscan: single block; exclusive scan of bcnt -> bstart, init bcur
// ---------------------------------------------------------------------------
__global__ __launch_bounds__(1024) void bscan_k(
    const int* __restrict__ bcnt, int* __restrict__ bstart,
    int* __restrict__ bcur, int E, int NBK)
{
    __shared__ int sd[1024];
    int t = threadIdx.x;
    int v0 = (t < NBK) ? bcnt[t] : 0;
    sd[t] = v0;
    __syncthreads();
    for (int st = 1; st < 1024; st <<= 1) {
        int v = (t >= st) ? sd[t - st] : 0;
        __syncthreads();
        sd[t] += v;
        __syncthreads();
    }
    int ex = sd[t] - v0;
    if (t < NBK) { bstart[t] = ex; bcur[t] = ex; }
    if (t == 0)  { bstart[NBK] = E; }
}

// ---------------------------------------------------------------------------
// S1: LDS-sorted tile scatter. Tile is bucket-sorted in LDS, then written out
//     coalesced. stg entry = {src | localdst<<17, tabidx}
// ---------------------------------------------------------------------------
__global__ __launch_bounds__(512) void s1_bucket(
    const int* __restrict__ ei, const float* __restrict__ t,
    const float* __restrict__ ntime,
    int* __restrict__ bcur, int2* __restrict__ stg, int E, int NBK)
{
    __shared__ int2 tile[TILE];       // 64 KB
    __shared__ int  lcnt[NBKMAX];     // counts
    __shared__ int  lcur[NBKMAX];     // scatter cursor (starts at lofs)
    __shared__ int  gdel[NBKMAX];     // gpos[b] - lofs[b]

    int tid = threadIdx.x;
    int base = blockIdx.x * TILE;
    int cnt_here = min(TILE, E - base);

    for (int i = tid; i < NBKMAX; i += 512) lcnt[i] = 0;
    __syncthreads();

    // phase A: per-bucket counts for this tile
#pragma unroll 4
    for (int i = 0; i < TILE / 512; ++i) {
        int e = base + i * 512 + tid;
        if (e < E) atomicAdd(&lcnt[((unsigned int)ei[E + e]) >> NBSH], 1);
    }
    __syncthreads();

    // block-wide exclusive scan of lcnt (two 512-chunks), reserve global runs
    {
        __shared__ int sd[512];
        __shared__ int carry;
        for (int half = 0; half < NBKMAX / 512; ++half) {
            int bi = half * 512 + tid;
            int v0 = lcnt[bi];
            sd[tid] = v0;
            __syncthreads();
            for (int st = 1; st < 512; st <<= 1) {
                int v = (tid >= st) ? sd[tid - st] : 0;
                __syncthreads();
                sd[tid] += v;
                __syncthreads();
            }
            int lofs = sd[tid] - v0 + (half ? carry : 0);
            if (bi < NBK) {
                int gpos = (v0 > 0) ? atomicAdd(&bcur[bi], v0) : 0;
                lcur[bi] = lofs;
                gdel[bi] = gpos - lofs;
            }
            if (tid == 511) carry = (half ? carry : 0) + sd[511];
            __syncthreads();
        }
    }

    // phase B: park entries in LDS at bucket-sorted ranks
#pragma unroll 4
    for (int i = 0; i < TILE / 512; ++i) {
        int e = base + i * 512 + tid;
        if (e < E) {
            int d = ei[E + e];
            int s = ei[e];
            float rel = ntime[s] - t[e];
            float u = fmaf(rel, (float)(TABK / 2), (float)(TABK / 2) + 0.5f);
            int idx = (int)u;
            idx = min(max(idx, 0), TABK - 1);
            int b = ((unsigned int)d) >> NBSH;
            int r = atomicAdd(&lcur[b], 1);
            tile[r] = make_int2(s | ((d & (BNODES - 1)) << 17),
                                idx | (b << 20));
        }
    }
    __syncthreads();

    // phase C: coalesced write-out
    for (int k = tid; k < cnt_here; k += 512) {
        int2 en = tile[k];
        int b = ((unsigned int)en.y) >> 20;
        stg[gdel[b] + k] = make_int2(en.x, en.y & 0xFFFFF);
    }
}

// ---------------------------------------------------------------------------
// fused_gather: one block per bucket (128 nodes). 8-lane group per edge,
// LDS float accumulators (padded strides for bank spread), fused epilogue.
// ---------------------------------------------------------------------------
__global__ __launch_bounds__(512) void fused_gather(
    const int* __restrict__ bstart, const int2* __restrict__ stg,
    const float* __restrict__ qn, const unsigned short* __restrict__ kvn,
    const float* __restrict__ skv, const float* __restrict__ table,
    const float* __restrict__ Wout, const float* __restrict__ bout,
    float* __restrict__ out, int N)
{
    __shared__ float lacc[BNODES * ASTR];   // 18944 B
    __shared__ float lq[BNODES * QSTR];     // 16896 B

    int tid = threadIdx.x;
    int sub = tid & 7;
    int nb0 = blockIdx.x << NBSH;
    int nodes = min(BNODES, N - nb0);

    for (int i = tid; i < BNODES * ASTR; i += 512) lacc[i] = 0.0f;
    for (int i = tid; i < nodes * DH; i += 512) {
        int nd = i >> 5, c = i & 31;
        lq[nd * QSTR + c] = qn[(size_t)(nb0 + nd) * DH + c];
    }
    __syncthreads();

    int lo = bstart[blockIdx.x];
    int hi = bstart[blockIdx.x + 1];

    int j = lo + (tid >> 3);
    int2 pl;
    if (j < hi) pl = stg[j];
    for (; j < hi; j += 64) {
        int2 cur = pl;
        if (j + 64 < hi) pl = stg[j + 64];   // prefetch next edge

        int src = cur.x & 0x1FFFF;
        int ld  = (cur.x >> 17) & (BNODES - 1);
        int idx = cur.y;

        const float4 ev = *(const float4*)(table + (size_t)idx * DH + sub * 4);
        const unsigned short* row = kvn + (size_t)src * 64;
        uint2 kb = *(const uint2*)(row + sub * 4);
        uint2 vb = *(const uint2*)(row + 32 + sub * 4);
        const float4 q4 = *(const float4*)&lq[ld * QSTR + sub * 4];

        float part = q4.x * (bfl(kb.x) + ev.x) + q4.y * (bfh(kb.x) + ev.y)
                   + q4.z * (bfl(kb.y) + ev.z) + q4.w * (bfh(kb.y) + ev.w);
        part += __shfl_xor(part, 1);
        part += __shfl_xor(part, 2);
        float wgt = __expf(part);   // 0.25 scale folded into q; logits tiny, no max

        float* ab = &lacc[ld * ASTR];
        atomicAdd(&ab[sub * 4 + 0], (bfl(vb.x) + ev.x) * wgt);
        atomicAdd(&ab[sub * 4 + 1], (bfh(vb.x) + ev.y) * wgt);
        atomicAdd(&ab[sub * 4 + 2], (bfl(vb.y) + ev.z) * wgt);
        atomicAdd(&ab[sub * 4 + 3], (bfh(vb.y) + ev.w) * wgt);
        if ((sub & 3) == 0) atomicAdd(&ab[32 + (sub >> 2)], wgt);
    }
    __syncthreads();

    // epilogue: 8 lanes per node, 64 nodes per pass, 2 passes
    const float4 w0v = *(const float4*)(Wout + sub * 4);
    const float4 w1v = *(const float4*)(Wout + DH + sub * 4);
#pragma unroll
    for (int p = 0; p < 2; ++p) {
        int node = p * 64 + (tid >> 3);
        int g = nb0 + node;
        if (node < nodes) {
            float* ab = &lacc[node * ASTR];
            float s0 = ab[32], s1 = ab[33];
            float r0 = (s0 > 0.0f) ? 1.0f / s0 : 0.0f;
            float r1 = (s1 > 0.0f) ? 1.0f / s1 : 0.0f;
            float r = (sub < 4) ? r0 : r1;
            float a0 = ab[sub * 4 + 0], a1 = ab[sub * 4 + 1];
            float a2 = ab[sub * 4 + 2], a3 = ab[sub * 4 + 3];
            const float4 sk = *(const float4*)(skv + (size_t)g * DH + sub * 4);
            float h0 = a0 * r + sk.x;
            float h1 = a1 * r + sk.y;
            float h2 = a2 * r + sk.z;
            float h3 = a3 * r + sk.w;

            float l0 = h0 * w0v.x + h1 * w0v.y + h2 * w0v.z + h3 * w0v.w;
            float l1 = h0 * w1v.x + h1 * w1v.y + h2 * w1v.z + h3 * w1v.w;
            l0 += __shfl_xor(l0, 1); l0 += __shfl_xor(l0, 2); l0 += __shfl_xor(l0, 4);
            l1 += __shfl_xor(l1, 1); l1 += __shfl_xor(l1, 2); l1 += __shfl_xor(l1, 4);

            if (sub == 0) {
                l0 += bout[0];
                l1 += bout[1];
                float m = fmaxf(l0, l1);
                float lse = m + logf(__expf(l0 - m) + __expf(l1 - m));
                float2 o; o.x = l0 - lse; o.y = l1 - lse;
                *(float2*)(out + (size_t)g * 2) = o;
            }
        }
    }
}

// ---------------------------------------------------------------------------
extern "C" void kernel_launch(void* const* d_in, const int* in_sizes, int n_in,
                              void* d_out, int out_size, void* d_ws, size_t ws_size,
                              hipStream_t stream)
{
    const float* x      = (const float*)d_in[0];
    const int*   ei     = (const int*)d_in[1];
    const float* t      = (const float*)d_in[2];
    const float* ntime  = (const float*)d_in[3];
    const float* freq   = (const float*)d_in[4];
    const float* phase  = (const float*)d_in[5];
    const float* Wl     = (const float*)d_in[6];
    const float* bl     = (const float*)d_in[7];
    const float* Wq     = (const float*)d_in[8];
    const float* bq     = (const float*)d_in[9];
    const float* Wk     = (const float*)d_in[10];
    const float* bk     = (const float*)d_in[11];
    const float* Wv     = (const float*)d_in[12];
    const float* bv     = (const float*)d_in[13];
    const float* We     = (const float*)d_in[14];
    const float* be     = (const float*)d_in[15];
    const float* Ws     = (const float*)d_in[16];
    const float* bs     = (const float*)d_in[17];
    const float* Wout   = (const float*)d_in[18];
    const float* bout   = (const float*)d_in[19];

    const int E = in_sizes[2];        // t has E elements
    const int N = in_sizes[3];        // node_time has N elements
    const int NBK = (N + BNODES - 1) >> NBSH;   // buckets of 128 nodes

    char* wsb = (char*)d_ws;
    int2*  stg  = (int2*)wsb;               wsb += (size_t)E * sizeof(int2);
    float* qn   = (float*)wsb;              wsb += (size_t)N * DH * 4;
    unsigned short* kvn = (unsigned short*)wsb; wsb += (size_t)N * 64 * 2;
    float* skv  = (float*)wsb;              wsb += (size_t)N * DH * 4;
    float* tab  = (float*)wsb;              wsb += (size_t)(TABK + 1) * DH * 4;
    int*   bcnt = (int*)wsb;                wsb += NBKMAX * 4;
    int*   bstart = (int*)wsb;              wsb += (NBKMAX + 1) * 4;
    int*   bcur = (int*)wsb;                wsb += NBKMAX * 4;

    float* out = (float*)d_out;

    int nblk = (N + 255) / 256;
    int tblk = (E + TILE - 1) / TILE;

    node_prep<<<nblk, 256, 0, stream>>>(x, Wl, bl, Wq, bq, Wk, bk, Wv, bv, Ws, bs,
                                        qn, kvn, skv, bcnt, N);
    build_table<<<(TABK + 64) / 64, 64, 0, stream>>>(We, be, freq, phase, tab);
    bcount_k<<<tblk, 256, 0, stream>>>(ei, bcnt, E, NBK);
    bscan_k<<<1, 1024, 0, stream>>>(bcnt, bstart, bcur, E, NBK);
    s1_bucket<<<tblk, 512, 0, stream>>>(ei, t, ntime, bcur, stg, E, NBK);
    fused_gather<<<NBK, 512, 0, stream>>>(bstart, stg, qn, kvn, skv, tab,
                                          Wout, bout, out, N);
}

// Round 9
// 238.384 us; speedup vs baseline: 3.6568x; 3.6568x over previous
//
#include <hip/hip_runtime.h>
#include <math.h>

// Problem constants (match reference)
#define D_IN 17
#define DH   32      // hidden dim = H*C
#define TDIM 32
#define TABK 4096    // time-encoding table resolution (nearest-neighbor)

#define NBSH 7                   // nodes per bucket = 128
#define BNODES (1 << NBSH)
#define NBKMAX 1024              // max buckets supported
#define TILE 8192                // edges per tile block (bcount / s1)
#define CAP  6144                // bucket_gather LDS tile capacity (edges)

// LDS weight pack offsets (floats) for node_prep
#define WL_OFF 0        // 32*17
#define BL_OFF 544
#define WQ_OFF 576      // 32*32
#define BQ_OFF 1600
#define WK_OFF 1632
#define BK_OFF 2656
#define WV_OFF 2688
#define BV_OFF 3712
#define WS_OFF 3744
#define BS_OFF 4768
#define WTOT   4800

__device__ __forceinline__ unsigned int f2bf(float x) {
    unsigned int u = __float_as_uint(x);
    return (u + 0x7fffu + ((u >> 16) & 1u)) >> 16;   // RTNE, no NaN expected
}
__device__ __forceinline__ float bfl(unsigned int u) { return __uint_as_float(u << 16); }
__device__ __forceinline__ float bfh(unsigned int u) { return __uint_as_float(u & 0xffff0000u); }

// ---------------------------------------------------------------------------
// Kernel 1: h1 = relu(x@Wl.T+bl); q (f32, pre-scaled by 0.25), k/v packed bf16
//           (128B/row), skip f32. block 0 also zeroes bcnt.
// ---------------------------------------------------------------------------
__global__ __launch_bounds__(256) void node_prep(
    const float* __restrict__ x,
    const float* __restrict__ Wl, const float* __restrict__ bl,
    const float* __restrict__ Wq, const float* __restrict__ bq,
    const float* __restrict__ Wk, const float* __restrict__ bk,
    const float* __restrict__ Wv, const float* __restrict__ bv,
    const float* __restrict__ Ws, const float* __restrict__ bs,
    float* __restrict__ qn, unsigned short* __restrict__ kvn,
    float* __restrict__ skv, int* __restrict__ bcnt, int N)
{
    if (blockIdx.x == 0) {
        for (int i = threadIdx.x; i < NBKMAX; i += 256) bcnt[i] = 0;
    }

    __shared__ float w[WTOT];
    {
        const float* srcs[10] = {Wl, bl, Wq, bq, Wk, bk, Wv, bv, Ws, bs};
        const int   sizes[10] = {544, 32, 1024, 32, 1024, 32, 1024, 32, 1024, 32};
        int off = 0;
        for (int seg = 0; seg < 10; ++seg) {
            const float* p = srcs[seg];
            int sz = sizes[seg];
            for (int i = threadIdx.x; i < sz; i += blockDim.x) w[off + i] = p[i];
            off += sz;
        }
    }
    __syncthreads();

    int n = blockIdx.x * blockDim.x + threadIdx.x;
    if (n >= N) return;

    float xv[D_IN];
#pragma unroll
    for (int j = 0; j < D_IN; ++j) xv[j] = x[(size_t)n * D_IN + j];

    float h1[DH];
#pragma unroll
    for (int i = 0; i < DH; ++i) {
        float acc = w[BL_OFF + i];
#pragma unroll
        for (int j = 0; j < D_IN; ++j) acc += xv[j] * w[WL_OFF + i * D_IN + j];
        h1[i] = fmaxf(acc, 0.0f);
    }

    float outr[DH];

#define MATVEC(WO, BO)                                                       \
    {                                                                        \
        _Pragma("unroll")                                                    \
        for (int i = 0; i < DH; ++i) {                                       \
            float acc = w[(BO) + i];                                         \
            _Pragma("unroll")                                                \
            for (int c = 0; c < 8; ++c) {                                    \
                float4 wv = *(const float4*)&w[(WO) + i * DH + c * 4];       \
                acc += h1[c * 4 + 0] * wv.x + h1[c * 4 + 1] * wv.y           \
                     + h1[c * 4 + 2] * wv.z + h1[c * 4 + 3] * wv.w;          \
            }                                                                \
            outr[i] = acc;                                                   \
        }                                                                    \
    }

    // q -> f32 (scaled by 1/sqrt(C)=0.25, folded here)
    MATVEC(WQ_OFF, BQ_OFF)
    {
        float4* dst4 = (float4*)(qn + (size_t)n * DH);
#pragma unroll
        for (int c = 0; c < 8; ++c) {
            float4 o; o.x = outr[c*4+0] * 0.25f; o.y = outr[c*4+1] * 0.25f;
            o.z = outr[c*4+2] * 0.25f; o.w = outr[c*4+3] * 0.25f;
            dst4[c] = o;
        }
    }

    // k -> bf16 packed words 0..15
    unsigned int kw[16], vw[16];
    MATVEC(WK_OFF, BK_OFF)
#pragma unroll
    for (int i = 0; i < 16; ++i)
        kw[i] = f2bf(outr[2*i]) | (f2bf(outr[2*i+1]) << 16);

    // v -> bf16 packed words 16..31
    MATVEC(WV_OFF, BV_OFF)
#pragma unroll
    for (int i = 0; i < 16; ++i)
        vw[i] = f2bf(outr[2*i]) | (f2bf(outr[2*i+1]) << 16);

    {
        uint4* row = (uint4*)(kvn + (size_t)n * 64);
#pragma unroll
        for (int c = 0; c < 4; ++c) {
            uint4 o; o.x = kw[c*4+0]; o.y = kw[c*4+1]; o.z = kw[c*4+2]; o.w = kw[c*4+3];
            row[c] = o;
        }
#pragma unroll
        for (int c = 0; c < 4; ++c) {
            uint4 o; o.x = vw[c*4+0]; o.y = vw[c*4+1]; o.z = vw[c*4+2]; o.w = vw[c*4+3];
            row[4 + c] = o;
        }
    }

    // skip -> f32
    MATVEC(WS_OFF, BS_OFF)
    {
        float4* dst4 = (float4*)(skv + (size_t)n * DH);
#pragma unroll
        for (int c = 0; c < 8; ++c) {
            float4 o; o.x = outr[c*4+0]; o.y = outr[c*4+1];
            o.z = outr[c*4+2]; o.w = outr[c*4+3];
            dst4[c] = o;
        }
    }
#undef MATVEC
}

// ---------------------------------------------------------------------------
// Kernel 2: time-encoding lookup table (TABK+1 rows, nearest-neighbor use)
// ---------------------------------------------------------------------------
__global__ __launch_bounds__(64) void build_table(
    const float* __restrict__ We, const float* __restrict__ be,
    const float* __restrict__ freq, const float* __restrict__ phase,
    float* __restrict__ table)
{
    int k = blockIdx.x * blockDim.x + threadIdx.x;
    if (k > TABK) return;
    float r = -1.0f + 2.0f * (float)k / (float)TABK;
    float cj[TDIM];
#pragma unroll
    for (int j = 0; j < TDIM; ++j) cj[j] = cosf(r * freq[j] + phase[j]);
#pragma unroll 4
    for (int o = 0; o < DH; ++o) {
        float acc = be[o];
#pragma unroll
        for (int j = 0; j < TDIM; ++j) acc += cj[j] * We[o * TDIM + j];
        table[(size_t)k * DH + o] = acc;
    }
}

// ---------------------------------------------------------------------------
// bcount: coarse-bucket histogram (LDS-aggregated)
// ---------------------------------------------------------------------------
__global__ __launch_bounds__(256) void bcount_k(
    const int* __restrict__ ei, int* __restrict__ bcnt, int E, int NBK)
{
    __shared__ int lc[NBKMAX];
    for (int i = threadIdx.x; i < NBKMAX; i += 256) lc[i] = 0;
    __syncthreads();
    int base = blockIdx.x * TILE;
#pragma unroll 4
    for (int i = 0; i < TILE / 256; ++i) {
        int e = base + i * 256 + threadIdx.x;
        if (e < E) atomicAdd(&lc[((unsigned int)ei[E + e]) >> NBSH], 1);
    }
    __syncthreads();
    for (int b = threadIdx.x; b < NBK; b += 256) {
        int c = lc[b];
        if (c) atomicAdd(&bcnt[b], c);
    }
}

// ---------------------------------------------------------------------------
// bscan: single block; exclusive scan of bcnt -> bstart, init bcur
// ---------------------------------------------------------------------------
__global__ __launch_bounds__(1024) void bscan_k(
    const int* __restrict__ bcnt, int* __restrict__ bstart,
    int* __restrict__ bcur, int E, int NBK)
{
    __shared__ int sd[1024];
    int t = threadIdx.x;
    int v0 = (t < NBK) ? bcnt[t] : 0;
    sd[t] = v0;
    __syncthreads();
    for (int st = 1; st < 1024; st <<= 1) {
        int v = (t >= st) ? sd[t - st] : 0;
        __syncthreads();
        sd[t] += v;
        __syncthreads();
    }
    int ex = sd[t] - v0;
    if (t < NBK) { bstart[t] = ex; bcur[t] = ex; }
    if (t == 0)  { bstart[NBK] = E; }
}

// ---------------------------------------------------------------------------
// S1: LDS-sorted tile scatter (1024 threads, single-pass 1024-wide scan).
//     stg entry = {src | localdst<<17, tabidx | bucket<<20}
// ---------------------------------------------------------------------------
__global__ __launch_bounds__(1024) void s1_bucket(
    const int* __restrict__ ei, const float* __restrict__ t,
    const float* __restrict__ ntime,
    int* __restrict__ bcur, int2* __restrict__ stg, int E, int NBK)
{
    __shared__ int2 tile[TILE];       // 64 KB
    __shared__ int  lcnt[NBKMAX];     // counts
    __shared__ int  lcur[NBKMAX];     // scatter cursor (starts at lofs)
    __shared__ int  gdel[NBKMAX];     // gpos[b] - lofs[b]
    __shared__ int  sd[1024];

    int tid = threadIdx.x;
    int base = blockIdx.x * TILE;
    int cnt_here = min(TILE, E - base);

    lcnt[tid] = 0;
    __syncthreads();

    // phase A: per-bucket counts for this tile
#pragma unroll
    for (int i = 0; i < TILE / 1024; ++i) {
        int e = base + i * 1024 + tid;
        if (e < E) atomicAdd(&lcnt[((unsigned int)ei[E + e]) >> NBSH], 1);
    }
    __syncthreads();

    // 1024-wide exclusive scan, reserve global runs
    {
        int v0 = lcnt[tid];
        sd[tid] = v0;
        __syncthreads();
        for (int st = 1; st < 1024; st <<= 1) {
            int v = (tid >= st) ? sd[tid - st] : 0;
            __syncthreads();
            sd[tid] += v;
            __syncthreads();
        }
        int lofs = sd[tid] - v0;
        if (tid < NBK) {
            int gpos = (v0 > 0) ? atomicAdd(&bcur[tid], v0) : 0;
            lcur[tid] = lofs;
            gdel[tid] = gpos - lofs;
        }
    }
    __syncthreads();

    // phase B: park entries in LDS at bucket-sorted ranks
#pragma unroll
    for (int i = 0; i < TILE / 1024; ++i) {
        int e = base + i * 1024 + tid;
        if (e < E) {
            int d = ei[E + e];
            int s = ei[e];
            float rel = ntime[s] - t[e];
            float u = fmaf(rel, (float)(TABK / 2), (float)(TABK / 2) + 0.5f);
            int idx = (int)u;
            idx = min(max(idx, 0), TABK - 1);
            int b = ((unsigned int)d) >> NBSH;
            int r = atomicAdd(&lcur[b], 1);
            tile[r] = make_int2(s | ((d & (BNODES - 1)) << 17),
                                idx | (b << 20));
        }
    }
    __syncthreads();

    // phase C: coalesced write-out
    for (int k = tid; k < cnt_here; k += 1024) {
        int2 en = tile[k];
        int b = ((unsigned int)en.y) >> 20;
        stg[gdel[b] + k] = make_int2(en.x, en.y & 0xFFFFF);
    }
}

// ---------------------------------------------------------------------------
// bucket_gather: one block per bucket (128 nodes). In-LDS node-sort of the
// bucket's run, then register-accumulated gather (16 groups x 32 lanes,
// 4 edge slots per group), fused epilogue. No global payload round-trip.
// ---------------------------------------------------------------------------
__global__ __launch_bounds__(512) void bucket_gather(
    const int* __restrict__ bstart, const int2* __restrict__ stg,
    const float* __restrict__ qn, const unsigned short* __restrict__ kvn,
    const float* __restrict__ skv, const float* __restrict__ table,
    const float* __restrict__ Wout, const float* __restrict__ bout,
    float* __restrict__ out, int N)
{
    __shared__ int2 tile[CAP];           // 48 KB, node-sorted edge records
    __shared__ int  lstart[BNODES + 1];
    __shared__ int  lcur[BNODES];
    __shared__ int  sc[BNODES];

    int tid = threadIdx.x;
    int nb0 = blockIdx.x << NBSH;
    int lo = bstart[blockIdx.x];
    int hi = bstart[blockIdx.x + 1];
    int cnt = hi - lo;
    int take = min(cnt, CAP);

    if (tid < BNODES) lcur[tid] = 0;
    __syncthreads();

    // pass 1: per-node histogram of staged run
    for (int i = tid; i < take; i += 512)
        atomicAdd(&lcur[(stg[lo + i].x >> 17) & (BNODES - 1)], 1);
    __syncthreads();

    // 128-wide inclusive scan -> exclusive starts
    if (tid < BNODES) sc[tid] = lcur[tid];
    __syncthreads();
    for (int st = 1; st < BNODES; st <<= 1) {
        int v = 0;
        if (tid < BNODES && tid >= st) v = sc[tid - st];
        __syncthreads();
        if (tid < BNODES) sc[tid] += v;
        __syncthreads();
    }
    if (tid < BNODES) {
        int ex = sc[tid] - lcur[tid];
        lstart[tid] = ex;
        lcur[tid] = ex;
    }
    if (tid == 0) lstart[BNODES] = take;
    __syncthreads();

    // pass 2: scatter into node-sorted LDS tile (stg re-read is L2-hot)
    for (int i = tid; i < take; i += 512) {
        int2 e = stg[lo + i];
        int ld = (e.x >> 17) & (BNODES - 1);
        int pos = atomicAdd(&lcur[ld], 1);
        tile[pos] = make_int2(e.x & 0x1FFFF, e.y);
    }
    __syncthreads();

    // phase 3: register-accumulated gather. group = 32 lanes, 4 edge slots.
    int grp  = tid >> 5;        // 0..15
    int slot = (tid >> 3) & 3;  // edge slot
    int sub  = tid & 7;         // channel group (4 floats)

    const float4 w0v = *(const float4*)(Wout + sub * 4);
    const float4 w1v = *(const float4*)(Wout + DH + sub * 4);
    float bo0 = bout[0], bo1 = bout[1];

    for (int ni = grp; ni < BNODES; ni += 16) {
        int g = nb0 + ni;
        if (g >= N) break;   // group-uniform

        int s0 = lstart[ni], s1e = lstart[ni + 1];
        const float4 q4 = *(const float4*)(qn + (size_t)g * DH + sub * 4);
        float4 acc; acc.x = acc.y = acc.z = acc.w = 0.0f;
        float ssum = 0.0f;

        for (int j = s0 + slot; j < s1e; j += 4) {
            int2 e = tile[j];
            int src = e.x;
            int idx = e.y;

            const float4 ev = *(const float4*)(table + (size_t)idx * DH + sub * 4);
            const unsigned short* row = kvn + (size_t)src * 64;
            uint2 kb = *(const uint2*)(row + sub * 4);
            uint2 vb = *(const uint2*)(row + 32 + sub * 4);

            float part = q4.x * (bfl(kb.x) + ev.x) + q4.y * (bfh(kb.x) + ev.y)
                       + q4.z * (bfl(kb.y) + ev.z) + q4.w * (bfh(kb.y) + ev.w);
            part += __shfl_xor(part, 1);
            part += __shfl_xor(part, 2);
            float wgt = __expf(part);   // 0.25 folded into q; logits tiny, no max
            ssum += wgt;

            acc.x += (bfl(vb.x) + ev.x) * wgt;
            acc.y += (bfh(vb.x) + ev.y) * wgt;
            acc.z += (bfl(vb.y) + ev.z) * wgt;
            acc.w += (bfh(vb.y) + ev.w) * wgt;
        }

        // rare overflow: edges beyond CAP processed straight from global
        if (cnt > take) {
            for (int j = lo + take + slot; j < hi; j += 4) {
                int2 e = stg[j];
                if (((e.x >> 17) & (BNODES - 1)) == ni) {
                    int src = e.x & 0x1FFFF;
                    int idx = e.y;
                    const float4 ev = *(const float4*)(table + (size_t)idx * DH + sub * 4);
                    const unsigned short* row = kvn + (size_t)src * 64;
                    uint2 kb = *(const uint2*)(row + sub * 4);
                    uint2 vb = *(const uint2*)(row + 32 + sub * 4);
                    float part = q4.x * (bfl(kb.x) + ev.x) + q4.y * (bfh(kb.x) + ev.y)
                               + q4.z * (bfl(kb.y) + ev.z) + q4.w * (bfh(kb.y) + ev.w);
                    part += __shfl_xor(part, 1);
                    part += __shfl_xor(part, 2);
                    float wgt = __expf(part);
                    ssum += wgt;
                    acc.x += (bfl(vb.x) + ev.x) * wgt;
                    acc.y += (bfh(vb.x) + ev.y) * wgt;
                    acc.z += (bfl(vb.y) + ev.z) * wgt;
                    acc.w += (bfh(vb.y) + ev.w) * wgt;
                }
            }
        }

        // combine the four edge slots
        acc.x += __shfl_xor(acc.x, 8);
        acc.y += __shfl_xor(acc.y, 8);
        acc.z += __shfl_xor(acc.z, 8);
        acc.w += __shfl_xor(acc.w, 8);
        ssum  += __shfl_xor(ssum, 8);
        acc.x += __shfl_xor(acc.x, 16);
        acc.y += __shfl_xor(acc.y, 16);
        acc.z += __shfl_xor(acc.z, 16);
        acc.w += __shfl_xor(acc.w, 16);
        ssum  += __shfl_xor(ssum, 16);

        float r = (ssum > 0.0f) ? 1.0f / ssum : 0.0f;
        const float4 sk = *(const float4*)(skv + (size_t)g * DH + sub * 4);
        float h0 = acc.x * r + sk.x;
        float h1 = acc.y * r + sk.y;
        float h2 = acc.z * r + sk.z;
        float h3 = acc.w * r + sk.w;

        float l0 = h0 * w0v.x + h1 * w0v.y + h2 * w0v.z + h3 * w0v.w;
        float l1 = h0 * w1v.x + h1 * w1v.y + h2 * w1v.z + h3 * w1v.w;
        l0 += __shfl_xor(l0, 1); l0 += __shfl_xor(l0, 2); l0 += __shfl_xor(l0, 4);
        l1 += __shfl_xor(l1, 1); l1 += __shfl_xor(l1, 2); l1 += __shfl_xor(l1, 4);

        if ((tid & 31) == 0) {
            l0 += bo0;
            l1 += bo1;
            float m = fmaxf(l0, l1);
            float lse = m + logf(__expf(l0 - m) + __expf(l1 - m));
            float2 o; o.x = l0 - lse; o.y = l1 - lse;
            *(float2*)(out + (size_t)g * 2) = o;
        }
    }
}

// ---------------------------------------------------------------------------
extern "C" void kernel_launch(void* const* d_in, const int* in_sizes, int n_in,
                              void* d_out, int out_size, void* d_ws, size_t ws_size,
                              hipStream_t stream)
{
    const float* x      = (const float*)d_in[0];
    const int*   ei     = (const int*)d_in[1];
    const float* t      = (const float*)d_in[2];
    const float* ntime  = (const float*)d_in[3];
    const float* freq   = (const float*)d_in[4];
    const float* phase  = (const float*)d_in[5];
    const float* Wl     = (const float*)d_in[6];
    const float* bl     = (const float*)d_in[7];
    const float* Wq     = (const float*)d_in[8];
    const float* bq     = (const float*)d_in[9];
    const float* Wk     = (const float*)d_in[10];
    const float* bk     = (const float*)d_in[11];
    const float* Wv     = (const float*)d_in[12];
    const float* bv     = (const float*)d_in[13];
    const float* We     = (const float*)d_in[14];
    const float* be     = (const float*)d_in[15];
    const float* Ws     = (const float*)d_in[16];
    const float* bs     = (const float*)d_in[17];
    const float* Wout   = (const float*)d_in[18];
    const float* bout   = (const float*)d_in[19];

    const int E = in_sizes[2];        // t has E elements
    const int N = in_sizes[3];        // node_time has N elements
    const int NBK = (N + BNODES - 1) >> NBSH;   // buckets of 128 nodes

    char* wsb = (char*)d_ws;
    int2*  stg  = (int2*)wsb;               wsb += (size_t)E * sizeof(int2);
    float* qn   = (float*)wsb;              wsb += (size_t)N * DH * 4;
    unsigned short* kvn = (unsigned short*)wsb; wsb += (size_t)N * 64 * 2;
    float* skv  = (float*)wsb;              wsb += (size_t)N * DH * 4;
    float* tab  = (float*)wsb;              wsb += (size_t)(TABK + 1) * DH * 4;
    int*   bcnt = (int*)wsb;                wsb += NBKMAX * 4;
    int*   bstart = (int*)wsb;              wsb += (NBKMAX + 1) * 4;
    int*   bcur = (int*)wsb;                wsb += NBKMAX * 4;

    float* out = (float*)d_out;

    int nblk = (N + 255) / 256;
    int tblk = (E + TILE - 1) / TILE;

    node_prep<<<nblk, 256, 0, stream>>>(x, Wl, bl, Wq, bq, Wk, bk, Wv, bv, Ws, bs,
                                        qn, kvn, skv, bcnt, N);
    build_table<<<(TABK + 64) / 64, 64, 0, stream>>>(We, be, freq, phase, tab);
    bcount_k<<<tblk, 256, 0, stream>>>(ei, bcnt, E, NBK);
    bscan_k<<<1, 1024, 0, stream>>>(bcnt, bstart, bcur, E, NBK);
    s1_bucket<<<tblk, 1024, 0, stream>>>(ei, t, ntime, bcur, stg, E, NBK);
    bucket_gather<<<NBK, 512, 0, stream>>>(bstart, stg, qn, kvn, skv, tab,
                                           Wout, bout, out, N);
}

// Round 10
// 220.840 us; speedup vs baseline: 3.9473x; 1.0794x over previous
//
#include <hip/hip_runtime.h>
#include <math.h>

// Problem constants (match reference)
#define D_IN 17
#define DH   32      // hidden dim = H*C
#define TDIM 32
#define TABK 1024    // time-encoding table resolution (nearest-neighbor)

#define NBSH 8                   // nodes per bucket = 256
#define BNODES (1 << NBSH)
#define NBKMAX 512               // max buckets supported
#define TILE 8192                // edges per tile block (bcount / s1)

// LDS weight pack offsets (floats) for node_prep
#define WL_OFF 0        // 32*17
#define BL_OFF 544
#define WQ_OFF 576      // 32*32
#define BQ_OFF 1600
#define WK_OFF 1632
#define BK_OFF 2656
#define WV_OFF 2688
#define BV_OFF 3712
#define WS_OFF 3744
#define BS_OFF 4768
#define WTOT   4800

__device__ __forceinline__ unsigned int f2bf(float x) {
    unsigned int u = __float_as_uint(x);
    return (u + 0x7fffu + ((u >> 16) & 1u)) >> 16;   // RTNE, no NaN expected
}
__device__ __forceinline__ float bfl(unsigned int u) { return __uint_as_float(u << 16); }
__device__ __forceinline__ float bfh(unsigned int u) { return __uint_as_float(u & 0xffff0000u); }

// ---------------------------------------------------------------------------
// Kernel 1: h1 = relu(x@Wl.T+bl); q (f32, pre-scaled by 0.25), k/v packed bf16
//           (128B/row), skip f32. block 0 also zeroes bcnt.
// ---------------------------------------------------------------------------
__global__ __launch_bounds__(256) void node_prep(
    const float* __restrict__ x,
    const float* __restrict__ Wl, const float* __restrict__ bl,
    const float* __restrict__ Wq, const float* __restrict__ bq,
    const float* __restrict__ Wk, const float* __restrict__ bk,
    const float* __restrict__ Wv, const float* __restrict__ bv,
    const float* __restrict__ Ws, const float* __restrict__ bs,
    float* __restrict__ qn, unsigned short* __restrict__ kvn,
    float* __restrict__ skv, int* __restrict__ bcnt, int N)
{
    if (blockIdx.x == 0) {
        for (int i = threadIdx.x; i < NBKMAX; i += 256) bcnt[i] = 0;
    }

    __shared__ float w[WTOT];
    {
        const float* srcs[10] = {Wl, bl, Wq, bq, Wk, bk, Wv, bv, Ws, bs};
        const int   sizes[10] = {544, 32, 1024, 32, 1024, 32, 1024, 32, 1024, 32};
        int off = 0;
        for (int seg = 0; seg < 10; ++seg) {
            const float* p = srcs[seg];
            int sz = sizes[seg];
            for (int i = threadIdx.x; i < sz; i += blockDim.x) w[off + i] = p[i];
            off += sz;
        }
    }
    __syncthreads();

    int n = blockIdx.x * blockDim.x + threadIdx.x;
    if (n >= N) return;

    float xv[D_IN];
#pragma unroll
    for (int j = 0; j < D_IN; ++j) xv[j] = x[(size_t)n * D_IN + j];

    float h1[DH];
#pragma unroll
    for (int i = 0; i < DH; ++i) {
        float acc = w[BL_OFF + i];
#pragma unroll
        for (int j = 0; j < D_IN; ++j) acc += xv[j] * w[WL_OFF + i * D_IN + j];
        h1[i] = fmaxf(acc, 0.0f);
    }

    float outr[DH];

#define MATVEC(WO, BO)                                                       \
    {                                                                        \
        _Pragma("unroll")                                                    \
        for (int i = 0; i < DH; ++i) {                                       \
            float acc = w[(BO) + i];                                         \
            _Pragma("unroll")                                                \
            for (int c = 0; c < 8; ++c) {                                    \
                float4 wv = *(const float4*)&w[(WO) + i * DH + c * 4];       \
                acc += h1[c * 4 + 0] * wv.x + h1[c * 4 + 1] * wv.y           \
                     + h1[c * 4 + 2] * wv.z + h1[c * 4 + 3] * wv.w;          \
            }                                                                \
            outr[i] = acc;                                                   \
        }                                                                    \
    }

    // q -> f32 (scaled by 1/sqrt(C)=0.25, folded here)
    MATVEC(WQ_OFF, BQ_OFF)
    {
        float4* dst4 = (float4*)(qn + (size_t)n * DH);
#pragma unroll
        for (int c = 0; c < 8; ++c) {
            float4 o; o.x = outr[c*4+0] * 0.25f; o.y = outr[c*4+1] * 0.25f;
            o.z = outr[c*4+2] * 0.25f; o.w = outr[c*4+3] * 0.25f;
            dst4[c] = o;
        }
    }

    // k -> bf16 packed words 0..15
    unsigned int kw[16], vw[16];
    MATVEC(WK_OFF, BK_OFF)
#pragma unroll
    for (int i = 0; i < 16; ++i)
        kw[i] = f2bf(outr[2*i]) | (f2bf(outr[2*i+1]) << 16);

    // v -> bf16 packed words 16..31
    MATVEC(WV_OFF, BV_OFF)
#pragma unroll
    for (int i = 0; i < 16; ++i)
        vw[i] = f2bf(outr[2*i]) | (f2bf(outr[2*i+1]) << 16);

    {
        uint4* row = (uint4*)(kvn + (size_t)n * 64);
#pragma unroll
        for (int c = 0; c < 4; ++c) {
            uint4 o; o.x = kw[c*4+0]; o.y = kw[c*4+1]; o.z = kw[c*4+2]; o.w = kw[c*4+3];
            row[c] = o;
        }
#pragma unroll
        for (int c = 0; c < 4; ++c) {
            uint4 o; o.x = vw[c*4+0]; o.y = vw[c*4+1]; o.z = vw[c*4+2]; o.w = vw[c*4+3];
            row[4 + c] = o;
        }
    }

    // skip -> f32
    MATVEC(WS_OFF, BS_OFF)
    {
        float4* dst4 = (float4*)(skv + (size_t)n * DH);
#pragma unroll
        for (int c = 0; c < 8; ++c) {
            float4 o; o.x = outr[c*4+0]; o.y = outr[c*4+1];
            o.z = outr[c*4+2]; o.w = outr[c*4+3];
            dst4[c] = o;
        }
    }
#undef MATVEC
}

// ---------------------------------------------------------------------------
// Kernel 2: time-encoding lookup table (TABK+1 rows, nearest-neighbor use)
// ---------------------------------------------------------------------------
__global__ __launch_bounds__(64) void build_table(
    const float* __restrict__ We, const float* __restrict__ be,
    const float* __restrict__ freq, const float* __restrict__ phase,
    float* __restrict__ table)
{
    int k = blockIdx.x * blockDim.x + threadIdx.x;
    if (k > TABK) return;
    float r = -1.0f + 2.0f * (float)k / (float)TABK;
    float cj[TDIM];
#pragma unroll
    for (int j = 0; j < TDIM; ++j) cj[j] = cosf(r * freq[j] + phase[j]);
#pragma unroll 4
    for (int o = 0; o < DH; ++o) {
        float acc = be[o];
#pragma unroll
        for (int j = 0; j < TDIM; ++j) acc += cj[j] * We[o * TDIM + j];
        table[(size_t)k * DH + o] = acc;
    }
}

// ---------------------------------------------------------------------------
// bcount: coarse-bucket histogram (LDS-aggregated)
// ---------------------------------------------------------------------------
__global__ __launch_bounds__(256) void bcount_k(
    const int* __restrict__ ei, int* __restrict__ bcnt, int E, int NBK)
{
    __shared__ int lc[NBKMAX];
    for (int i = threadIdx.x; i < NBKMAX; i += 256) lc[i] = 0;
    __syncthreads();
    int base = blockIdx.x * TILE;
#pragma unroll 4
    for (int i = 0; i < TILE / 256; ++i) {
        int e = base + i * 256 + threadIdx.x;
        if (e < E) atomicAdd(&lc[((unsigned int)ei[E + e]) >> NBSH], 1);
    }
    __syncthreads();
    for (int b = threadIdx.x; b < NBK; b += 256) {
        int c = lc[b];
        if (c) atomicAdd(&bcnt[b], c);
    }
}

// ---------------------------------------------------------------------------
// bscan: single block; exclusive scan of bcnt -> bstart, init bcur, off[N]=E
// ---------------------------------------------------------------------------
__global__ __launch_bounds__(512) void bscan_k(
    const int* __restrict__ bcnt, int* __restrict__ bstart,
    int* __restrict__ bcur, int* __restrict__ off, int N, int E, int NBK)
{
    __shared__ int sd[512];
    int t = threadIdx.x;
    int v0 = (t < NBK) ? bcnt[t] : 0;
    sd[t] = v0;
    __syncthreads();
    for (int st = 1; st < 512; st <<= 1) {
        int v = (t >= st) ? sd[t - st] : 0;
        __syncthreads();
        sd[t] += v;
        __syncthreads();
    }
    int ex = sd[t] - v0;
    if (t < NBK) { bstart[t] = ex; bcur[t] = ex; }
    if (t == 0)  { bstart[NBK] = E; off[N] = E; }
}

// ---------------------------------------------------------------------------
// S1: LDS-sorted tile scatter; coalesced SoA write-out (4B + 2B per edge).
//     tile entry = {src | localdst<<17, tabidx | bucket<<20}
// ---------------------------------------------------------------------------
__global__ __launch_bounds__(512) void s1_bucket(
    const int* __restrict__ ei, const float* __restrict__ t,
    const float* __restrict__ ntime,
    int* __restrict__ bcur, int* __restrict__ stgA,
    unsigned short* __restrict__ stgB, int E, int NBK)
{
    __shared__ int2 tile[TILE];       // 64 KB
    __shared__ int  lcnt[NBKMAX];     // counts
    __shared__ int  lcur[NBKMAX];     // scatter cursor (starts at lofs)
    __shared__ int  gdel[NBKMAX];     // gpos[b] - lofs[b]

    int tid = threadIdx.x;
    int base = blockIdx.x * TILE;
    int cnt_here = min(TILE, E - base);

    lcnt[tid] = 0;                    // NBKMAX == blockDim
    __syncthreads();

    // phase A: per-bucket counts for this tile
#pragma unroll 4
    for (int i = 0; i < TILE / 512; ++i) {
        int e = base + i * 512 + tid;
        if (e < E) atomicAdd(&lcnt[((unsigned int)ei[E + e]) >> NBSH], 1);
    }
    __syncthreads();

    // 512-wide exclusive scan, reserve global runs
    {
        __shared__ int sd[512];
        int v0 = lcnt[tid];
        sd[tid] = v0;
        __syncthreads();
        for (int st = 1; st < 512; st <<= 1) {
            int v = (tid >= st) ? sd[tid - st] : 0;
            __syncthreads();
            sd[tid] += v;
            __syncthreads();
        }
        int lofs = sd[tid] - v0;
        if (tid < NBK) {
            int gpos = (v0 > 0) ? atomicAdd(&bcur[tid], v0) : 0;
            lcur[tid] = lofs;
            gdel[tid] = gpos - lofs;
        }
    }
    __syncthreads();

    // phase B: park entries in LDS at bucket-sorted ranks
#pragma unroll 4
    for (int i = 0; i < TILE / 512; ++i) {
        int e = base + i * 512 + tid;
        if (e < E) {
            int d = ei[E + e];
            int s = ei[e];
            float rel = ntime[s] - t[e];
            float u = fmaf(rel, (float)(TABK / 2), (float)(TABK / 2) + 0.5f);
            int idx = (int)u;
            idx = min(max(idx, 0), TABK - 1);
            int b = ((unsigned int)d) >> NBSH;
            int r = atomicAdd(&lcur[b], 1);
            tile[r] = make_int2(s | ((d & (BNODES - 1)) << 17),
                                idx | (b << 20));
        }
    }
    __syncthreads();

    // phase C: coalesced SoA write-out
    for (int k = tid; k < cnt_here; k += 512) {
        int2 en = tile[k];
        int b = ((unsigned int)en.y) >> 20;
        int gp = gdel[b] + k;
        stgA[gp] = en.x;
        stgB[gp] = (unsigned short)(en.y & 0x3FF);
    }
}

// ---------------------------------------------------------------------------
// S2: per-bucket LDS histogram + scan -> off[]; scatter 4B payload
//     payload = src | tabidx<<17
// ---------------------------------------------------------------------------
__global__ __launch_bounds__(512) void s2_hist_scatter(
    const int* __restrict__ bstart, const int* __restrict__ stgA,
    const unsigned short* __restrict__ stgB,
    int* __restrict__ payload, int* __restrict__ off, int N)
{
    __shared__ int lcnt[BNODES];
    __shared__ int sc[BNODES];
    int t = threadIdx.x;
    int nb0 = blockIdx.x << NBSH;
    if (t < BNODES) lcnt[t] = 0;
    __syncthreads();

    int lo = bstart[blockIdx.x];
    int hi = bstart[blockIdx.x + 1];

    // pass 1: local histogram (4B reads)
    for (int i = lo + t; i < hi; i += 512)
        atomicAdd(&lcnt[(stgA[i] >> 17) & (BNODES - 1)], 1);
    __syncthreads();

    // 256-wide inclusive scan (threads 0..255 active between barriers)
    if (t < BNODES) sc[t] = lcnt[t];
    __syncthreads();
    for (int st = 1; st < BNODES; st <<= 1) {
        int v = 0;
        if (t < BNODES && t >= st) v = sc[t - st];
        __syncthreads();
        if (t < BNODES) sc[t] += v;
        __syncthreads();
    }
    if (t < BNODES) {
        int gpos = lo + sc[t] - lcnt[t];
        if (nb0 + t < N) off[nb0 + t] = gpos;
        lcnt[t] = gpos;      // becomes the scatter cursor
    }
    __syncthreads();

    // pass 2: scatter to final position (stg run is L2-hot)
    for (int i = lo + t; i < hi; i += 512) {
        int a = stgA[i];
        int ld = (a >> 17) & (BNODES - 1);
        int pos = atomicAdd(&lcnt[ld], 1);
        payload[pos] = (a & 0x1FFFF) | ((int)stgB[i] << 17);
    }
}

// ---------------------------------------------------------------------------
// gather + finalize. 16 lanes per dst: 4 edge slots x 4 channel-lanes
// (8 channels each). No atomics.
// ---------------------------------------------------------------------------
__global__ __launch_bounds__(256) void gather_pass(
    const int* __restrict__ off, const int* __restrict__ payload,
    const float* __restrict__ qn, const unsigned short* __restrict__ kvn,
    const float* __restrict__ skv, const float* __restrict__ table,
    const float* __restrict__ Wout, const float* __restrict__ bout,
    float* __restrict__ out, int N)
{
    int tid = blockIdx.x * blockDim.x + threadIdx.x;
    int d    = tid >> 4;         // 16 lanes per dst
    int slot = (tid >> 2) & 3;   // edge slot 0..3
    int sub  = tid & 3;          // channel block: 8 floats
    if (d >= N) return;

    int qb = sub * 8;            // first channel owned by this lane
    const float4 qa = *(const float4*)(qn + d * DH + qb);
    const float4 qc = *(const float4*)(qn + d * DH + qb + 4);

    float a0 = 0, a1 = 0, a2 = 0, a3 = 0, a4 = 0, a5 = 0, a6 = 0, a7 = 0;
    float ssum = 0.0f;

    int beg = off[d];
    int end = off[d + 1];
    int j = beg + slot;
    int p = (j < end) ? payload[j] : 0;
    for (; j < end; j += 4) {
        int pc = p;
        if (j + 4 < end) p = payload[j + 4];   // prefetch next edge

        int src = pc & 0x1FFFF;
        int idx = ((unsigned int)pc) >> 17;

        const float* tr = table + idx * DH + qb;
        float4 e0 = *(const float4*)tr;
        float4 e1 = *(const float4*)(tr + 4);
        const unsigned short* row = kvn + src * 64 + sub * 8;
        uint4 kb = *(const uint4*)row;
        uint4 vb = *(const uint4*)(row + 32);

        float part = qa.x * (bfl(kb.x) + e0.x) + qa.y * (bfh(kb.x) + e0.y)
                   + qa.z * (bfl(kb.y) + e0.z) + qa.w * (bfh(kb.y) + e0.w)
                   + qc.x * (bfl(kb.z) + e1.x) + qc.y * (bfh(kb.z) + e1.y)
                   + qc.z * (bfl(kb.w) + e1.z) + qc.w * (bfh(kb.w) + e1.w);
        part += __shfl_xor(part, 1);   // pair sub{0,1}=head0, sub{2,3}=head1
        float wgt = __expf(part);      // 0.25 folded into q; logits tiny, no max
        ssum += wgt;

        a0 += (bfl(vb.x) + e0.x) * wgt;
        a1 += (bfh(vb.x) + e0.y) * wgt;
        a2 += (bfl(vb.y) + e0.z) * wgt;
        a3 += (bfh(vb.y) + e0.w) * wgt;
        a4 += (bfl(vb.z) + e1.x) * wgt;
        a5 += (bfh(vb.z) + e1.y) * wgt;
        a6 += (bfl(vb.w) + e1.z) * wgt;
        a7 += (bfh(vb.w) + e1.w) * wgt;
    }

    // combine the four edge slots (lanes xor 4, xor 8)
#define COMB(dist)                                                           \
    a0 += __shfl_xor(a0, dist); a1 += __shfl_xor(a1, dist);                  \
    a2 += __shfl_xor(a2, dist); a3 += __shfl_xor(a3, dist);                  \
    a4 += __shfl_xor(a4, dist); a5 += __shfl_xor(a5, dist);                  \
    a6 += __shfl_xor(a6, dist); a7 += __shfl_xor(a7, dist);                  \
    ssum += __shfl_xor(ssum, dist);
    COMB(4)
    COMB(8)
#undef COMB

    float r = (ssum > 0.0f) ? 1.0f / ssum : 0.0f;   // own head's denominator
    const float4 ska = *(const float4*)(skv + d * DH + qb);
    const float4 skc = *(const float4*)(skv + d * DH + qb + 4);
    float h0 = a0 * r + ska.x;
    float h1 = a1 * r + ska.y;
    float h2 = a2 * r + ska.z;
    float h3 = a3 * r + ska.w;
    float h4 = a4 * r + skc.x;
    float h5 = a5 * r + skc.y;
    float h6 = a6 * r + skc.z;
    float h7 = a7 * r + skc.w;

    const float4 w0a = *(const float4*)(Wout + qb);
    const float4 w0c = *(const float4*)(Wout + qb + 4);
    const float4 w1a = *(const float4*)(Wout + DH + qb);
    const float4 w1c = *(const float4*)(Wout + DH + qb + 4);
    float l0 = h0 * w0a.x + h1 * w0a.y + h2 * w0a.z + h3 * w0a.w
             + h4 * w0c.x + h5 * w0c.y + h6 * w0c.z + h7 * w0c.w;
    float l1 = h0 * w1a.x + h1 * w1a.y + h2 * w1a.z + h3 * w1a.w
             + h4 * w1c.x + h5 * w1c.y + h6 * w1c.z + h7 * w1c.w;
    l0 += __shfl_xor(l0, 1); l0 += __shfl_xor(l0, 2);
    l1 += __shfl_xor(l1, 1); l1 += __shfl_xor(l1, 2);

    if ((tid & 15) == 0) {
        l0 += bout[0];
        l1 += bout[1];
        float m = fmaxf(l0, l1);
        float lse = m + logf(__expf(l0 - m) + __expf(l1 - m));
        float2 o; o.x = l0 - lse; o.y = l1 - lse;
        *(float2*)(out + d * 2) = o;
    }
}

// ---------------------------------------------------------------------------
extern "C" void kernel_launch(void* const* d_in, const int* in_sizes, int n_in,
                              void* d_out, int out_size, void* d_ws, size_t ws_size,
                              hipStream_t stream)
{
    const float* x      = (const float*)d_in[0];
    const int*   ei     = (const int*)d_in[1];
    const float* t      = (const float*)d_in[2];
    const float* ntime  = (const float*)d_in[3];
    const float* freq   = (const float*)d_in[4];
    const float* phase  = (const float*)d_in[5];
    const float* Wl     = (const float*)d_in[6];
    const float* bl     = (const float*)d_in[7];
    const float* Wq     = (const float*)d_in[8];
    const float* bq     = (const float*)d_in[9];
    const float* Wk     = (const float*)d_in[10];
    const float* bk     = (const float*)d_in[11];
    const float* Wv     = (const float*)d_in[12];
    const float* bv     = (const float*)d_in[13];
    const float* We     = (const float*)d_in[14];
    const float* be     = (const float*)d_in[15];
    const float* Ws     = (const float*)d_in[16];
    const float* bs     = (const float*)d_in[17];
    const float* Wout   = (const float*)d_in[18];
    const float* bout   = (const float*)d_in[19];

    const int E = in_sizes[2];        // t has E elements
    const int N = in_sizes[3];        // node_time has N elements
    const int NBK = (N + BNODES - 1) >> NBSH;   // buckets of 256 nodes

    char* wsb = (char*)d_ws;
    int*   stgA    = (int*)wsb;             wsb += (size_t)E * 4;
    unsigned short* stgB = (unsigned short*)wsb; wsb += (size_t)E * 2;
    wsb = (char*)(((size_t)wsb + 15) & ~(size_t)15);
    int*   payload = (int*)wsb;             wsb += (size_t)E * 4;
    float* qn   = (float*)wsb;              wsb += (size_t)N * DH * 4;
    unsigned short* kvn = (unsigned short*)wsb; wsb += (size_t)N * 64 * 2;
    float* skv  = (float*)wsb;              wsb += (size_t)N * DH * 4;
    float* tab  = (float*)wsb;              wsb += (size_t)(TABK + 1) * DH * 4;
    int*   off  = (int*)wsb;                wsb += (size_t)(N + 1) * 4;
    int*   bcnt = (int*)wsb;                wsb += NBKMAX * 4;
    int*   bstart = (int*)wsb;              wsb += (NBKMAX + 1) * 4;
    int*   bcur = (int*)wsb;                wsb += NBKMAX * 4;

    float* out = (float*)d_out;

    int nblk = (N + 255) / 256;
    int tblk = (E + TILE - 1) / TILE;

    node_prep<<<nblk, 256, 0, stream>>>(x, Wl, bl, Wq, bq, Wk, bk, Wv, bv, Ws, bs,
                                        qn, kvn, skv, bcnt, N);
    build_table<<<(TABK + 64) / 64, 64, 0, stream>>>(We, be, freq, phase, tab);
    bcount_k<<<tblk, 256, 0, stream>>>(ei, bcnt, E, NBK);
    bscan_k<<<1, 512, 0, stream>>>(bcnt, bstart, bcur, off, N, E, NBK);
    s1_bucket<<<tblk, 512, 0, stream>>>(ei, t, ntime, bcur, stgA, stgB, E, NBK);
    s2_hist_scatter<<<NBK, 512, 0, stream>>>(bstart, stgA, stgB, payload, off, N);

    int gblk = ((size_t)N * 16 + 255) / 256;
    gather_pass<<<gblk, 256, 0, stream>>>(off, payload, qn, kvn, skv,
                                          tab, Wout, bout, out, N);
}